// Round 2
// baseline (535.297 us; speedup 1.0000x reference)
//
#include <hip/hip_runtime.h>

typedef unsigned short u16;
typedef unsigned int u32;
typedef __attribute__((ext_vector_type(8))) u16 u16x8;
typedef __attribute__((ext_vector_type(8))) __bf16 bf16x8;
typedef __attribute__((ext_vector_type(4))) float f32x4;

#define CIN 128
#define NB 4
#define NN 4096
#define KPTS 16
#define COUT 256
#define POSB 65536      // NN*KPTS
#define TOTPOS 262144   // NB*POSB
#define CK 2304         // 9*256

__device__ __forceinline__ float bf2f(u16 u){ return __uint_as_float(((u32)u)<<16); }
__device__ __forceinline__ u16 f2bf(float f){
  u32 u = __float_as_uint(f);
  u32 r = (u + 0x7fffu + ((u>>16)&1u)) >> 16;   // RNE
  return (u16)r;
}

// ---- 1. pack conv_w [256][256][3][3] f32 -> wp[co][tap*256+ci] bf16
__global__ void pack_w_kernel(const float* __restrict__ w, u16* __restrict__ wp){
  int t = blockIdx.x*256 + threadIdx.x;
  if (t >= COUT*CK) return;
  int co = t / CK; int r = t - co*CK; int tap = r >> 8; int ci = r & 255;
  wp[t] = f2bf(w[(co*256 + ci)*9 + tap]);
}

// ---- 2. transpose+cast x,y [B][128][4096] f32 -> xt,yt [B][4096][128] bf16
__global__ void transpose_cast_kernel(const float* __restrict__ x, const float* __restrict__ y,
                                      u16* __restrict__ xt, u16* __restrict__ yt){
  __shared__ u16 tile[2][32][65];
  int n0 = blockIdx.x*64, c0 = blockIdx.y*32, b = blockIdx.z;
  int t = threadIdx.x;
  int tn = t & 63, tc = t >> 6;
  #pragma unroll
  for (int i=0;i<8;++i){
    int c = tc*8 + i;
    size_t src = ((size_t)(b*CIN + c0 + c))*NN + n0 + tn;
    tile[0][c][tn] = f2bf(x[src]);
    tile[1][c][tn] = f2bf(y[src]);
  }
  __syncthreads();
  int tcc = t & 31, tnn = t >> 5;
  #pragma unroll
  for (int i=0;i<8;++i){
    int n = tnn*8 + i;
    size_t dst = ((size_t)(b*NN + n0 + n))*CIN + c0 + tcc;
    xt[dst] = tile[0][tcc][n];
    yt[dst] = tile[1][tcc][n];
  }
}

// element offset into a [row][32] bf16 tile with 16B-chunk XOR swizzle
#define SWZ(row, chunk) (((row)*32) + ((((chunk) ^ (((row)>>1)&3))) << 3))

// ---- 3. fused gather + implicit-GEMM conv + bias + (max over k -> maxout) + BN stats
// out[b,co,pos] = sum_{tap,ci} W[co][tap,ci]*Hvirt[pos+shift][ci], Hvirt = [x_i | x_j-x_i]
__global__ __launch_bounds__(256) void conv_gemm_kernel(const u16* __restrict__ wp,
    const int* __restrict__ e, const u16* __restrict__ xt, const u16* __restrict__ yt,
    const float* __restrict__ bias, float* __restrict__ ssum, float* __restrict__ ssq,
    float* __restrict__ maxout){
  __shared__ u16 alds[2][128*32];
  __shared__ u16 blds[2][128*32];

  int bid = blockIdx.x;
  int co_half = (bid >> 3) & 1;                      // pair same-ptile blocks 8 apart (same XCD)
  int ptile = (bid & 7) | ((bid >> 4) << 3);         // 0..2047
  int p0 = ptile * 128;                              // global position base
  int b = p0 >> 16;
  int pib0 = p0 & (POSB-1);
  int nb0 = pib0 >> 4;                               // n-base within batch (8 n's per block)

  int t = threadIdx.x;
  int lane = t & 63, wave = t >> 6;
  int wr = wave >> 1, wc = wave & 1;
  int sidx = t >> 1, shalf = t & 1;

  int co_base = co_half*128;
  const u16* wsrc0 = wp + (size_t)(co_base + sidx)*CK + shalf*16;
  int pib_s = pib0 + sidx;
  int n_s = pib_s >> 4, k_s = pib_s & 15;
  const int* ep0 = e + p0 + sidx;                    // edge_index[0] plane
  const int* ep1 = ep0 + TOTPOS;                     // edge_index[1] plane
  const u16* xb = xt + ((size_t)b)*NN*CIN;
  const u16* yb = yt + ((size_t)b)*NN*CIN;

  f32x4 acc[4][4];
  #pragma unroll
  for (int i=0;i<4;++i)
    #pragma unroll
    for (int j=0;j<4;++j) acc[i][j] = (f32x4){0.f,0.f,0.f,0.f};

  u16x8 areg0, areg1, breg0, breg1;

  auto LOAD = [&](int ks){
    int tap = ks >> 3, cg = ks & 7;
    const u16* wsrc = wsrc0 + tap*256 + (cg<<5);
    areg0 = *(const u16x8*)(wsrc);
    areg1 = *(const u16x8*)(wsrc + 8);
    int tdiv3 = (tap*11) >> 5;                       // tap/3 for tap in [0,9)
    int dn = tdiv3 - 1, dk = tap - tdiv3*3 - 1;
    int nn = n_s + dn, kk = k_s + dk;
    u16x8 zz = {0,0,0,0,0,0,0,0};
    breg0 = zz; breg1 = zz;
    if ( ((unsigned)nn < (unsigned)NN) & ((unsigned)kk < (unsigned)KPTS) ){
      int doff = dn*16 + dk;
      int j1 = ep1[doff];                            // x_i source (from x)
      int c = (cg<<5) + shalf*16;
      if (cg < 4){
        const u16* src = xb + (size_t)j1*CIN + c;
        breg0 = *(const u16x8*)src;
        breg1 = *(const u16x8*)(src + 8);
      } else {
        int j0 = ep0[doff];                          // x_j source (from y)
        const u16* sx = xb + (size_t)j1*CIN + (c - 128);
        const u16* sy = yb + (size_t)j0*CIN + (c - 128);
        u16x8 xv0 = *(const u16x8*)sx, xv1 = *(const u16x8*)(sx + 8);
        u16x8 yv0 = *(const u16x8*)sy, yv1 = *(const u16x8*)(sy + 8);
        #pragma unroll
        for (int q=0;q<8;++q){
          breg0[q] = f2bf(bf2f(yv0[q]) - bf2f(xv0[q]));
          breg1[q] = f2bf(bf2f(yv1[q]) - bf2f(xv1[q]));
        }
      }
    }
  };

  auto WRITE = [&](int buf){
    int c0 = shalf*2;
    *(u16x8*)&alds[buf][SWZ(sidx, c0)]   = areg0;
    *(u16x8*)&alds[buf][SWZ(sidx, c0+1)] = areg1;
    *(u16x8*)&blds[buf][SWZ(sidx, c0)]   = breg0;
    *(u16x8*)&blds[buf][SWZ(sidx, c0+1)] = breg1;
  };

  LOAD(0);
  WRITE(0);
  __syncthreads();

  int l15 = lane & 15, l4 = lane >> 4;
  int aoff[4], boff[4];
  #pragma unroll
  for (int f=0; f<4; ++f){
    int arow = wr*64 + f*16 + l15;
    aoff[f] = SWZ(arow, l4);
    int brow = wc*64 + f*16 + l15;
    boff[f] = SWZ(brow, l4);
  }

  for (int ks = 0; ks < 72; ++ks){
    int cur = ks & 1;
    if (ks+1 < 72) LOAD(ks+1);
    bf16x8 af[4], bfv[4];
    #pragma unroll
    for (int f=0; f<4; ++f){
      af[f]  = *(bf16x8*)&alds[cur][aoff[f]];
      bfv[f] = *(bf16x8*)&blds[cur][boff[f]];
    }
    #pragma unroll
    for (int fm=0; fm<4; ++fm)
      #pragma unroll
      for (int fn=0; fn<4; ++fn)
        acc[fm][fn] = __builtin_amdgcn_mfma_f32_16x16x32_bf16(af[fm], bfv[fn], acc[fm][fn], 0, 0, 0);
    if (ks+1 < 72) WRITE(cur ^ 1);
    __syncthreads();
  }

  // ---- epilogue: bias + max over k (l15) + per-channel sum/sumsq
  float* fs = (float*)&alds[0][0];       // fs[0..128) = sum, fs[128..256) = sumsq
  fs[t & 255] = 0.f;
  __syncthreads();

  #pragma unroll
  for (int fm=0; fm<4; ++fm){
    #pragma unroll
    for (int j=0; j<4; ++j){
      int ch = wr*64 + fm*16 + l4*4 + j;             // channel local to block
      int co_g = co_base + ch;
      float bv = bias[co_g];
      float s = 0.f, q = 0.f;
      float mv[4];
      #pragma unroll
      for (int fn=0; fn<4; ++fn){
        float v = acc[fm][fn][j] + bv;
        s += v; q += v*v; mv[fn] = v;
      }
      #pragma unroll
      for (int o=1; o<16; o<<=1){
        s += __shfl_xor(s, o, 64);
        q += __shfl_xor(q, o, 64);
        #pragma unroll
        for (int fn=0; fn<4; ++fn) mv[fn] = fmaxf(mv[fn], __shfl_xor(mv[fn], o, 64));
      }
      if (l15 == 0){
        atomicAdd(&fs[ch], s);
        atomicAdd(&fs[128 + ch], q);
        size_t rowb = ((size_t)(b*COUT + co_g)) << 12;
        #pragma unroll
        for (int fn=0; fn<4; ++fn)
          maxout[rowb + nb0 + wc*4 + fn] = mv[fn];
      }
    }
  }
  __syncthreads();
  if (t < 128)      atomicAdd(&ssum[co_base + t], fs[t]);
  else if (t < 256) atomicAdd(&ssq[co_base + t - 128], fs[t]);
}

// ---- 4. finalize BN scale/shift
__global__ void finalize_stats_kernel(const float* __restrict__ ssum, const float* __restrict__ ssq,
                                      const float* __restrict__ gamma, const float* __restrict__ beta,
                                      float* __restrict__ scale, float* __restrict__ shift){
  int co = threadIdx.x;
  float inv = 1.0f / (float)TOTPOS;
  float mean = ssum[co]*inv;
  float var = ssq[co]*inv - mean*mean;
  float sc = gamma[co] * rsqrtf(var + 1e-5f);
  scale[co] = sc;
  shift[co] = beta[co] - mean*sc;
}

// ---- 5. in-place BN + ReLU on maxout (valid since scale>0: max/relu commute with affine)
__global__ void bn_finish_kernel(float* __restrict__ out, const float* __restrict__ scale,
                                 const float* __restrict__ shift){
  int t = blockIdx.x*256 + threadIdx.x;              // (b*COUT+co)*NN + n
  int co = (t >> 12) & 255;
  float v = out[t];
  out[t] = fmaxf(fmaf(scale[co], v, shift[co]), 0.f);
}

extern "C" void kernel_launch(void* const* d_in, const int* in_sizes, int n_in,
                              void* d_out, int out_size, void* d_ws, size_t ws_size,
                              hipStream_t stream){
  const float* x = (const float*)d_in[0];
  const float* y = (const float*)d_in[1];
  const int*   e = (const int*)d_in[2];
  const float* w = (const float*)d_in[3];
  const float* bias = (const float*)d_in[4];
  const float* gamma = (const float*)d_in[5];
  const float* beta  = (const float*)d_in[6];
  float* out = (float*)d_out;

  char* ws = (char*)d_ws;                  // total footprint: ~9.6 MB
  u16*   wp    = (u16*)(ws);               // 1,179,648 B
  float* ssum  = (float*)(ws + 1179648);   // 1 KB
  float* ssq   = (float*)(ws + 1180672);   // 1 KB
  float* scale = (float*)(ws + 1181696);   // 1 KB
  float* shift = (float*)(ws + 1182720);   // 1 KB
  u16*   xt    = (u16*)(ws + 1183744);     // 4 MB
  u16*   yt    = (u16*)(ws + 5378048);     // 4 MB  (end: 9,572,352)

  hipMemsetAsync(ssum, 0, 2048, stream);   // zero ssum+ssq every call (deterministic)

  pack_w_kernel<<<2304, 256, 0, stream>>>(w, wp);
  dim3 tg(NN/64, CIN/32, NB);
  transpose_cast_kernel<<<tg, 256, 0, stream>>>(x, y, xt, yt);
  conv_gemm_kernel<<<4096, 256, 0, stream>>>(wp, e, xt, yt, bias, ssum, ssq, out);
  finalize_stats_kernel<<<1, COUT, 0, stream>>>(ssum, ssq, gamma, beta, scale, shift);
  bn_finish_kernel<<<out_size/256, 256, 0, stream>>>(out, scale, shift);
}

// Round 3
// 424.803 us; speedup vs baseline: 1.2601x; 1.2601x over previous
//
#include <hip/hip_runtime.h>

typedef unsigned short u16;
typedef unsigned int u32;
typedef __attribute__((ext_vector_type(8))) u16 u16x8;
typedef __attribute__((ext_vector_type(8))) __bf16 bf16x8;
typedef __attribute__((ext_vector_type(4))) float f32x4;

#define CIN 128
#define NB 4
#define NN 4096
#define KPTS 16
#define COUT 256
#define POSB 65536      // NN*KPTS
#define TOTPOS 262144   // NB*POSB
#define CK 2304         // 9*256

__device__ __forceinline__ float bf2f(u16 u){ return __uint_as_float(((u32)u)<<16); }
__device__ __forceinline__ u16 f2bf(float f){
  u32 u = __float_as_uint(f);
  u32 r = (u + 0x7fffu + ((u>>16)&1u)) >> 16;   // RNE
  return (u16)r;
}

// ---- 1. pack conv_w with the U/V transform:
//   out = W_left@x_i + W_right@(x_j - x_i) = (W_left-W_right)@x_i + W_right@x_j
//   wp[co][tap*256 + c]:  c<128 -> U[co][tap][c] = Wl - Wr;  c>=128 -> V = Wr
__global__ void pack_w_kernel(const float* __restrict__ w, u16* __restrict__ wp){
  int t = blockIdx.x*256 + threadIdx.x;
  if (t >= COUT*CK) return;
  int co = t / CK; int r = t - co*CK; int tap = r >> 8; int c = r & 255;
  float v;
  if (c < 128)
    v = w[(co*256 + c)*9 + tap] - w[(co*256 + 128 + c)*9 + tap];
  else
    v = w[(co*256 + c)*9 + tap];
  wp[t] = f2bf(v);
}

// ---- 2. transpose+cast x,y [B][128][4096] f32 -> xt,yt [B][4096][128] bf16
__global__ void transpose_cast_kernel(const float* __restrict__ x, const float* __restrict__ y,
                                      u16* __restrict__ xt, u16* __restrict__ yt){
  __shared__ u16 tile[2][32][65];
  int n0 = blockIdx.x*64, c0 = blockIdx.y*32, b = blockIdx.z;
  int t = threadIdx.x;
  int tn = t & 63, tc = t >> 6;
  #pragma unroll
  for (int i=0;i<8;++i){
    int c = tc*8 + i;
    size_t src = ((size_t)(b*CIN + c0 + c))*NN + n0 + tn;
    tile[0][c][tn] = f2bf(x[src]);
    tile[1][c][tn] = f2bf(y[src]);
  }
  __syncthreads();
  int tcc = t & 31, tnn = t >> 5;
  #pragma unroll
  for (int i=0;i<8;++i){
    int n = tnn*8 + i;
    size_t dst = ((size_t)(b*NN + n0 + n))*CIN + c0 + tcc;
    xt[dst] = tile[0][tcc][n];
    yt[dst] = tile[1][tcc][n];
  }
}

// element offset into a [row][32] bf16 tile with 16B-chunk XOR swizzle
#define SWZ(row, chunk) (((row)*32) + ((((chunk) ^ (((row)>>1)&3))) << 3))

// ---- 3. fused gather + implicit-GEMM conv + bias + (max over k -> maxout) + BN stats
__global__ __launch_bounds__(256) void conv_gemm_kernel(const u16* __restrict__ wp,
    const int* __restrict__ e, const u16* __restrict__ xt, const u16* __restrict__ yt,
    const u16* __restrict__ zrow, const float* __restrict__ bias,
    float* __restrict__ ssum, float* __restrict__ ssq, float* __restrict__ maxout){
  __shared__ u16 alds[2][128*32];
  __shared__ u16 blds[2][128*32];

  int bid = blockIdx.x;
  int co_half = (bid >> 3) & 1;                      // pair same-ptile blocks 8 apart (same XCD)
  int ptile = (bid & 7) | ((bid >> 4) << 3);         // 0..2047
  int p0 = ptile * 128;                              // global position base
  int b = p0 >> 16;
  int pib0 = p0 & (POSB-1);
  int nb0 = pib0 >> 4;                               // n-base within batch (8 n's per block)

  int t = threadIdx.x;
  int lane = t & 63, wave = t >> 6;
  int wr = wave >> 1, wc = wave & 1;
  int sidx = t >> 1, shalf = t & 1;

  int co_base = co_half*128;
  const u16* wsrc0 = wp + (size_t)(co_base + sidx)*CK + shalf*16;
  int pib_s = pib0 + sidx;
  int n_s = pib_s >> 4, k_s = pib_s & 15;
  const int* ebase0 = e + p0 + sidx;                 // edge_index[0] plane (x_j from y)
  const int* ebase1 = ebase0 + TOTPOS;               // edge_index[1] plane (x_i from x)
  const u16* xb = xt + ((size_t)b)*NN*CIN;
  const u16* yb = yt + ((size_t)b)*NN*CIN;

  f32x4 acc[4][4];
  #pragma unroll
  for (int i=0;i<4;++i)
    #pragma unroll
    for (int j=0;j<4;++j) acc[i][j] = (f32x4){0.f,0.f,0.f,0.f};

  u16x8 areg0, areg1, breg0, breg1;

  // per-tap gather base pointers (held in named scalars, recomputed once per 8 K-steps)
  auto TAPOFF = [&](int tap, const u16*& px, const u16*& py){
    int tdiv3 = (tap*11) >> 5;                       // tap/3 for tap in [0,9)
    int dn = tdiv3 - 1, dk = tap - tdiv3*3 - 1;
    int nn = n_s + dn, kk = k_s + dk;
    bool valid = ((unsigned)nn < (unsigned)NN) & ((unsigned)kk < (unsigned)KPTS);
    int j1 = 0, j0 = 0;
    if (valid){
      int doff = dn*16 + dk;
      j1 = ebase1[doff];
      j0 = ebase0[doff];
    }
    px = valid ? (xb + (size_t)j1*CIN) : zrow;
    py = valid ? (yb + (size_t)j0*CIN) : zrow;
  };

  auto LOADW = [&](int ko){
    areg0 = *(const u16x8*)(wsrc0 + ko);
    areg1 = *(const u16x8*)(wsrc0 + ko + 8);
  };
  auto LOADB = [&](const u16* src){
    breg0 = *(const u16x8*)(src);
    breg1 = *(const u16x8*)(src + 8);
  };
  auto WRITE = [&](int buf){
    int c0 = shalf*2;
    *(u16x8*)&alds[buf][SWZ(sidx, c0)]   = areg0;
    *(u16x8*)&alds[buf][SWZ(sidx, c0+1)] = areg1;
    *(u16x8*)&blds[buf][SWZ(sidx, c0)]   = breg0;
    *(u16x8*)&blds[buf][SWZ(sidx, c0+1)] = breg1;
  };

  const u16 *px, *py, *pxn = zrow, *pyn = zrow;
  TAPOFF(0, px, py);
  LOADW(0);
  LOADB(px + shalf*16);
  WRITE(0);
  __syncthreads();

  int l15 = lane & 15, l4 = lane >> 4;
  int aoff[4], boff[4];
  #pragma unroll
  for (int f=0; f<4; ++f){
    aoff[f] = SWZ(wr*64 + f*16 + l15, l4);
    boff[f] = SWZ(wc*64 + f*16 + l15, l4);
  }

  for (int tap = 0; tap < 9; ++tap){
    if (tap < 8) TAPOFF(tap+1, pxn, pyn);            // issued 8 steps ahead of use
    int wbase = tap*256;
    #pragma unroll
    for (int cg = 0; cg < 8; ++cg){
      int cur = cg & 1;                              // tap*8 is even -> parity = cg&1
      bool has_next = (cg < 7) || (tap < 8);
      if (has_next){
        if (cg < 7){
          int ncg = cg + 1;
          LOADW(wbase + ncg*32);
          LOADB((ncg < 4 ? px : py) + (ncg & 3)*32 + shalf*16);
        } else {
          LOADW(wbase + 256);
          LOADB(pxn + shalf*16);
        }
      }
      bf16x8 af[4], bfv[4];
      #pragma unroll
      for (int f=0; f<4; ++f){
        af[f]  = *(bf16x8*)&alds[cur][aoff[f]];
        bfv[f] = *(bf16x8*)&blds[cur][boff[f]];
      }
      #pragma unroll
      for (int fm=0; fm<4; ++fm)
        #pragma unroll
        for (int fn=0; fn<4; ++fn)
          acc[fm][fn] = __builtin_amdgcn_mfma_f32_16x16x32_bf16(af[fm], bfv[fn], acc[fm][fn], 0, 0, 0);
      if (has_next) WRITE(cur ^ 1);
      __syncthreads();
    }
    px = pxn; py = pyn;
  }

  // ---- epilogue: bias + max over k (l15) + per-channel sum/sumsq
  float* fs = (float*)&alds[0][0];       // fs[0..128) = sum, fs[128..256) = sumsq
  fs[t & 255] = 0.f;
  __syncthreads();

  #pragma unroll
  for (int fm=0; fm<4; ++fm){
    #pragma unroll
    for (int j=0; j<4; ++j){
      int ch = wr*64 + fm*16 + l4*4 + j;             // channel local to block
      int co_g = co_base + ch;
      float bv = bias[co_g];
      float s = 0.f, q = 0.f;
      float mv[4];
      #pragma unroll
      for (int fn=0; fn<4; ++fn){
        float v = acc[fm][fn][j] + bv;
        s += v; q += v*v; mv[fn] = v;
      }
      #pragma unroll
      for (int o=1; o<16; o<<=1){
        s += __shfl_xor(s, o, 64);
        q += __shfl_xor(q, o, 64);
        #pragma unroll
        for (int fn=0; fn<4; ++fn) mv[fn] = fmaxf(mv[fn], __shfl_xor(mv[fn], o, 64));
      }
      if (l15 == 0){
        atomicAdd(&fs[ch], s);
        atomicAdd(&fs[128 + ch], q);
        size_t rowb = ((size_t)(b*COUT + co_g)) << 12;
        #pragma unroll
        for (int fn=0; fn<4; ++fn)
          maxout[rowb + nb0 + wc*4 + fn] = mv[fn];
      }
    }
  }
  __syncthreads();
  if (t < 128)      atomicAdd(&ssum[co_base + t], fs[t]);
  else if (t < 256) atomicAdd(&ssq[co_base + t - 128], fs[t]);
}

// ---- 4. finalize BN scale/shift
__global__ void finalize_stats_kernel(const float* __restrict__ ssum, const float* __restrict__ ssq,
                                      const float* __restrict__ gamma, const float* __restrict__ beta,
                                      float* __restrict__ scale, float* __restrict__ shift){
  int co = threadIdx.x;
  float inv = 1.0f / (float)TOTPOS;
  float mean = ssum[co]*inv;
  float var = ssq[co]*inv - mean*mean;
  float sc = gamma[co] * rsqrtf(var + 1e-5f);
  scale[co] = sc;
  shift[co] = beta[co] - mean*sc;
}

// ---- 5. in-place BN + ReLU on maxout (valid since scale>0: max/relu commute with affine)
__global__ void bn_finish_kernel(float* __restrict__ out, const float* __restrict__ scale,
                                 const float* __restrict__ shift){
  int t = blockIdx.x*256 + threadIdx.x;              // (b*COUT+co)*NN + n
  int co = (t >> 12) & 255;
  float v = out[t];
  out[t] = fmaxf(fmaf(scale[co], v, shift[co]), 0.f);
}

extern "C" void kernel_launch(void* const* d_in, const int* in_sizes, int n_in,
                              void* d_out, int out_size, void* d_ws, size_t ws_size,
                              hipStream_t stream){
  const float* x = (const float*)d_in[0];
  const float* y = (const float*)d_in[1];
  const int*   e = (const int*)d_in[2];
  const float* w = (const float*)d_in[3];
  const float* bias = (const float*)d_in[4];
  const float* gamma = (const float*)d_in[5];
  const float* beta  = (const float*)d_in[6];
  float* out = (float*)d_out;

  char* ws = (char*)d_ws;                  // total footprint: ~9.6 MB
  u16*   wp    = (u16*)(ws);               // 1,179,648 B
  float* ssum  = (float*)(ws + 1179648);   // 1 KB
  float* ssq   = (float*)(ws + 1180672);   // 1 KB
  u16*   zrow  = (u16*)(ws + 1181696);     // 1 KB (zero row: first 256 B used)
  float* scale = (float*)(ws + 1182720);   // 1 KB
  float* shift = (float*)(ws + 1183744);   // 1 KB
  u16*   xt    = (u16*)(ws + 1184768);     // 4 MB
  u16*   yt    = (u16*)(ws + 5379072);     // 4 MB  (end: 9,573,376)

  hipMemsetAsync(ssum, 0, 3072, stream);   // zero ssum+ssq+zrow every call (deterministic)

  pack_w_kernel<<<2304, 256, 0, stream>>>(w, wp);
  dim3 tg(NN/64, CIN/32, NB);
  transpose_cast_kernel<<<tg, 256, 0, stream>>>(x, y, xt, yt);
  conv_gemm_kernel<<<4096, 256, 0, stream>>>(wp, e, xt, yt, zrow, bias, ssum, ssq, out);
  finalize_stats_kernel<<<1, COUT, 0, stream>>>(ssum, ssq, gamma, beta, scale, shift);
  bn_finish_kernel<<<out_size/256, 256, 0, stream>>>(out, scale, shift);
}